// Round 5
// baseline (233.220 us; speedup 1.0000x reference)
//
#include <hip/hip_runtime.h>
#include <math.h>

constexpr int B = 256, STEP = 32, DF = 256, DZ = 64;
constexpr int TI = 16;                   // i-tile per k_z block
constexpr int NBLK_Z = (B / TI) * STEP;  // 512
#define LOG_2PI 1.837877066409345f
#define LOG_C   16.36495572888985f       // log(256 * 50000)

__device__ __forceinline__ float warpReduceSum64(float v) {
    for (int o = 32; o > 0; o >>= 1) v += __shfl_down(v, o, 64);
    return v;
}

// 256-thread block reduction; lds4 = float[4]; result valid in ALL threads.
__device__ __forceinline__ float blockReduceSum256(float v, float* lds4) {
    int wid = threadIdx.x >> 6, lane = threadIdx.x & 63;
    v = warpReduceSum64(v);
    if (lane == 0) lds4[wid] = v;
    __syncthreads();
    float r = lds4[0] + lds4[1] + lds4[2] + lds4[3];
    __syncthreads();
    return r;
}

// 512-thread block reductions; lds8 = float[8].
__device__ __forceinline__ float blockReduceSum512(float v, float* lds8) {
    int wid = threadIdx.x >> 6, lane = threadIdx.x & 63;
    v = warpReduceSum64(v);
    if (lane == 0) lds8[wid] = v;
    __syncthreads();
    float r = 0.0f;
#pragma unroll
    for (int k = 0; k < 8; ++k) r += lds8[k];
    __syncthreads();
    return r;
}
__device__ __forceinline__ float blockReduceMax512(float v, float* lds8) {
    int wid = threadIdx.x >> 6, lane = threadIdx.x & 63;
    for (int o = 32; o > 0; o >>= 1) v = fmaxf(v, __shfl_down(v, o, 64));
    if (lane == 0) lds8[wid] = v;
    __syncthreads();
    float r = -INFINITY;
#pragma unroll
    for (int k = 0; k < 8; ++k) r = fmaxf(r, lds8[k]);
    __syncthreads();
    return r;
}

// k_pre: tiled LDS transpose with transform. Coalesced reads AND writes.
//  blocks 0..127:  z: (s = b>>2, j0 = (b&3)*64) -> ezt[s][d][j] (d rows 0..63 = e,
//                  64..127 = m*e), wc[s*B+j] = sum(2lv) + DZ*log2pi.
//  blocks 128..131: f: j0 = (b-128)*64 -> eft[d][j] (rows 0..255 = e, 256..511 = m*e),
//                  wcf[j] = sum(2lv) + DF*log2pi.
__global__ __launch_bounds__(256) void k_pre(
        const float* __restrict__ fm, const float* __restrict__ fl,
        const float* __restrict__ zm, const float* __restrict__ zl,
        float* __restrict__ ezt, float* __restrict__ wc,
        float* __restrict__ eft, float* __restrict__ wcf,
        int* __restrict__ counter) {
    int t = threadIdx.x;
    int wv = t >> 6, ln = t & 63;
    __shared__ float te[64][65], tme[64][65];   // padded: conflict-free both axes
    if (blockIdx.x == 0 && t == 0) *counter = 0;

    if (blockIdx.x < 128) {
        int s = blockIdx.x >> 2, j0 = (blockIdx.x & 3) * 64;
#pragma unroll 4
        for (int it = 0; it < 16; ++it) {
            int jr = it * 4 + wv, j = j0 + jr;
            size_t src = ((size_t)j * STEP + s) * DZ + ln;   // 256B coalesced per wave
            float lv = zl[src], m = zm[src];
            float e = __expf(-lv);
            te[ln][jr] = e;
            tme[ln][jr] = m * e;
            float r = warpReduceSum64(2.0f * lv);
            if (ln == 0) wc[s * B + j] = r + (float)DZ * LOG_2PI;
        }
        __syncthreads();
#pragma unroll 4
        for (int it = 0; it < 16; ++it) {
            int dr = it * 4 + wv;
            ezt[((size_t)s * 128 + dr) * B + j0 + ln] = te[dr][ln];       // 256B coalesced
            ezt[((size_t)s * 128 + 64 + dr) * B + j0 + ln] = tme[dr][ln];
        }
    } else {
        int j0 = (blockIdx.x - 128) * 64;
        __shared__ float wsh[64];
        if (t < 64) wsh[t] = 0.0f;
        __syncthreads();
        for (int dt = 0; dt < 4; ++dt) {
            int d0 = dt * 64;
#pragma unroll 4
            for (int it = 0; it < 16; ++it) {
                int jr = it * 4 + wv, j = j0 + jr;
                size_t src = (size_t)j * DF + d0 + ln;
                float lv = fl[src], m = fm[src];
                float e = __expf(-lv);
                te[ln][jr] = e;
                tme[ln][jr] = m * e;
                float r = warpReduceSum64(2.0f * lv);
                if (ln == 0) wsh[jr] += r;     // same thread each dt -> deterministic
            }
            __syncthreads();
#pragma unroll 4
            for (int it = 0; it < 16; ++it) {
                int dr = it * 4 + wv;
                eft[(size_t)(d0 + dr) * B + j0 + ln] = te[dr][ln];
                eft[(size_t)(256 + d0 + dr) * B + j0 + ln] = tme[dr][ln];
            }
            __syncthreads();
        }
        if (t < 64) wcf[j0 + t] = wsh[t] + (float)DF * LOG_2PI;
    }
}

// k_f: grid = B (i), block = 512 (t = half*256 + j). All eft loads scalar-coalesced.
__global__ __launch_bounds__(512) void k_f(
        const float* __restrict__ fs, const float* __restrict__ eft,
        const float* __restrict__ wcf,
        float* __restrict__ sum_f, float* __restrict__ hneg_f) {
    int i = blockIdx.x, t = threadIdx.x;
    int j = t & (B - 1), half = t >> 8;
    __shared__ float fs_sh[DF];
    __shared__ float pacc[2][B];
    __shared__ float lds8[8];
    if (t < DF) fs_sh[t] = fs[(size_t)i * DF + t];
    __syncthreads();

    const float* ep = eft + (size_t)(half * 128) * B + j;         // e rows
    const float* mp = eft + (size_t)(256 + half * 128) * B + j;   // me rows
    const float4* fs4 = reinterpret_cast<const float4*>(fs_sh) + half * 32;
    float acc = 0.0f;
#pragma unroll 8
    for (int c = 0; c < 32; ++c) {
        float4 sv = fs4[c];
        float e0 = ep[(size_t)(c * 4 + 0) * B], e1 = ep[(size_t)(c * 4 + 1) * B];
        float e2 = ep[(size_t)(c * 4 + 2) * B], e3 = ep[(size_t)(c * 4 + 3) * B];
        float m0 = mp[(size_t)(c * 4 + 0) * B], m1 = mp[(size_t)(c * 4 + 1) * B];
        float m2 = mp[(size_t)(c * 4 + 2) * B], m3 = mp[(size_t)(c * 4 + 3) * B];
        float t0 = fmaf(sv.x, e0, -m0);
        float t1 = fmaf(sv.y, e1, -m1);
        float t2 = fmaf(sv.z, e2, -m2);
        float t3 = fmaf(sv.w, e3, -m3);
        acc = fmaf(t0, t0, acc); acc = fmaf(t1, t1, acc);
        acc = fmaf(t2, t2, acc); acc = fmaf(t3, t3, acc);
    }
    pacc[half][j] = acc;
    __syncthreads();

    float val = -INFINITY;
    if (t < B) {
        val = -0.5f * (pacc[0][j] + pacc[1][j] + wcf[j]);
        sum_f[(size_t)i * B + j] = val;
    }
    float m = blockReduceMax512(val, lds8);
    float ssum = blockReduceSum512(t < B ? __expf(val - m) : 0.0f, lds8);
    if (t == 0) hneg_f[i] = fmaxf(-(m + __logf(ssum) - LOG_C), 0.0f);
}

// k_z: grid = (B/TI, STEP), block = 256 (j). Coalesced ezt reads; wave-level LSE;
// fused deterministic final reduction (counter self-resets each call).
__global__ __launch_bounds__(256) void k_z(
        const float* __restrict__ ezt, const float* __restrict__ wc,
        const float* __restrict__ zs,
        const float* __restrict__ sum_f, const float* __restrict__ hneg_f,
        float* __restrict__ partials, int* __restrict__ counter,
        float* __restrict__ out) {
    int it = blockIdx.x, s = blockIdx.y, j = threadIdx.x;
    int i0 = it * TI;
    int bid = s * (B / TI) + it;
    int wv = j >> 6, ln = j & 63;
    __shared__ float zs_sh[TI][DZ];            // 4 KB
    __shared__ float wm[4][TI][2], ws_[4][TI][2];
    __shared__ float hbuf[2 * TI];
    __shared__ float lds4[4];
    __shared__ int   is_last;

    {   // stage TI zs rows (each row 256B contiguous; 16-lane groups coalesced)
        int ii = j >> 4, c = j & 15;
        float4 v = *reinterpret_cast<const float4*>(
            &zs[((size_t)(i0 + ii) * STEP + s) * DZ + c * 4]);
        *reinterpret_cast<float4*>(&zs_sh[ii][c * 4]) = v;
    }
    __syncthreads();

    const float* ep = ezt + (size_t)s * 128 * B + j;   // e rows, lane-coalesced
    const float* mp = ep + (size_t)64 * B;             // me rows
    float acc[TI];
#pragma unroll
    for (int i = 0; i < TI; ++i) acc[i] = 0.0f;
#pragma unroll
    for (int c = 0; c < 16; ++c) {
        float e0 = ep[(size_t)(c * 4 + 0) * B], e1 = ep[(size_t)(c * 4 + 1) * B];
        float e2 = ep[(size_t)(c * 4 + 2) * B], e3 = ep[(size_t)(c * 4 + 3) * B];
        float m0 = mp[(size_t)(c * 4 + 0) * B], m1 = mp[(size_t)(c * 4 + 1) * B];
        float m2 = mp[(size_t)(c * 4 + 2) * B], m3 = mp[(size_t)(c * 4 + 3) * B];
#pragma unroll
        for (int i = 0; i < TI; ++i) {
            float4 sv = *reinterpret_cast<const float4*>(&zs_sh[i][c * 4]);  // broadcast
            float t0 = fmaf(sv.x, e0, -m0);
            float t1 = fmaf(sv.y, e1, -m1);
            float t2 = fmaf(sv.z, e2, -m2);
            float t3 = fmaf(sv.w, e3, -m3);
            acc[i] = fmaf(t0, t0, acc[i]);
            acc[i] = fmaf(t1, t1, acc[i]);
            acc[i] = fmaf(t2, t2, acc[i]);
            acc[i] = fmaf(t3, t3, acc[i]);
        }
    }
    float wcj = wc[s * B + j];

    // Per-wave LSE over this wave's 64 j's, then 4-way combine.
#pragma unroll
    for (int i = 0; i < TI; ++i) {
        float sz = -0.5f * (acc[i] + wcj);
        float szf = sz + sum_f[(size_t)(i0 + i) * B + j];
        float m = sz;
        for (int o = 32; o > 0; o >>= 1) m = fmaxf(m, __shfl_xor(m, o, 64));
        float p = __expf(sz - m);
        for (int o = 32; o > 0; o >>= 1) p += __shfl_xor(p, o, 64);
        if (ln == 0) { wm[wv][i][0] = m; ws_[wv][i][0] = p; }
        float m2 = szf;
        for (int o = 32; o > 0; o >>= 1) m2 = fmaxf(m2, __shfl_xor(m2, o, 64));
        float p2 = __expf(szf - m2);
        for (int o = 32; o > 0; o >>= 1) p2 += __shfl_xor(p2, o, 64);
        if (ln == 0) { wm[wv][i][1] = m2; ws_[wv][i][1] = p2; }
    }
    __syncthreads();

    if (j < 2 * TI) {
        int i = j >> 1, ty = j & 1;
        float m0 = wm[0][i][ty], m1 = wm[1][i][ty], m2 = wm[2][i][ty], m3 = wm[3][i][ty];
        float mm = fmaxf(fmaxf(m0, m1), fmaxf(m2, m3));
        float ss = ws_[0][i][ty] * __expf(m0 - mm) + ws_[1][i][ty] * __expf(m1 - mm)
                 + ws_[2][i][ty] * __expf(m2 - mm) + ws_[3][i][ty] * __expf(m3 - mm);
        float lq = mm + __logf(ss) - LOG_C;
        hbuf[j] = fmaxf(-lq, 0.0f);
    }
    __syncthreads();

    if (j == 0) {
        float pz = 0.0f, pfz = 0.0f;
#pragma unroll
        for (int i = 0; i < TI; ++i) { pz += hbuf[2 * i]; pfz += hbuf[2 * i + 1]; }
        __hip_atomic_store(&partials[2 * bid], pz, __ATOMIC_RELAXED, __HIP_MEMORY_SCOPE_AGENT);
        __hip_atomic_store(&partials[2 * bid + 1], pfz, __ATOMIC_RELAXED, __HIP_MEMORY_SCOPE_AGENT);
        __threadfence();
        int old = __hip_atomic_fetch_add(counter, 1, __ATOMIC_ACQ_REL, __HIP_MEMORY_SCOPE_AGENT);
        is_last = (old == NBLK_Z - 1) ? 1 : 0;
    }
    __syncthreads();

    if (is_last) {
        __threadfence();
        float pz = 0.0f, pfz = 0.0f;
#pragma unroll
        for (int r = 0; r < NBLK_Z / B; ++r) {    // 2 per thread
            int b = r * B + j;
            pz  += __hip_atomic_load(&partials[2 * b], __ATOMIC_RELAXED, __HIP_MEMORY_SCOPE_AGENT);
            pfz += __hip_atomic_load(&partials[2 * b + 1], __ATOMIC_RELAXED, __HIP_MEMORY_SCOPE_AGENT);
        }
        float hf = hneg_f[j];
        float Hz  = blockReduceSum256(pz, lds4) * (1.0f / (STEP * B));
        float Hfz = blockReduceSum256(pfz, lds4) * (1.0f / (STEP * B));
        float Hf  = blockReduceSum256(hf, lds4) * (1.0f / B);
        if (j == 0) {
            out[0] = Hf + Hz - Hfz;
            __hip_atomic_store(counter, 0, __ATOMIC_RELEASE, __HIP_MEMORY_SCOPE_AGENT);
        }
    }
}

extern "C" void kernel_launch(void* const* d_in, const int* in_sizes, int n_in,
                              void* d_out, int out_size, void* d_ws, size_t ws_size,
                              hipStream_t stream) {
    const float* f_mean   = (const float*)d_in[0];
    const float* f_logvar = (const float*)d_in[1];
    const float* f_sample = (const float*)d_in[2];
    const float* z_mean   = (const float*)d_in[3];
    const float* z_logvar = (const float*)d_in[4];
    const float* z_sample = (const float*)d_in[5];
    float* out = (float*)d_out;

    float* w = (float*)d_ws;
    float* sum_f    = w;  w += B * B;               // 65536
    float* hneg_f   = w;  w += B;                   // 256
    float* partials = w;  w += 2 * NBLK_Z;          // 1024
    int*   counter  = (int*)w;  w += 64;            // padded
    float* ezt      = w;  w += STEP * 2 * DZ * B;   // 1048576 (4 MB), [s][128][256]
    float* wc       = w;  w += STEP * B;            // 8192
    float* eft      = w;  w += 2 * DF * B;          // 131072, [512][256]
    float* wcf      = w;  w += B;                   // 256

    k_pre<<<dim3(132), dim3(256), 0, stream>>>(f_mean, f_logvar, z_mean, z_logvar,
                                               ezt, wc, eft, wcf, counter);
    k_f<<<dim3(B), dim3(512), 0, stream>>>(f_sample, eft, wcf, sum_f, hneg_f);
    k_z<<<dim3(B / TI, STEP), dim3(256), 0, stream>>>(ezt, wc, z_sample,
                                                      sum_f, hneg_f, partials,
                                                      counter, out);
}

// Round 6
// 98.899 us; speedup vs baseline: 2.3582x; 2.3582x over previous
//
#include <hip/hip_runtime.h>
#include <math.h>

constexpr int B = 256, STEP = 32, DF = 256, DZ = 64;
constexpr int TI = 8;                    // i-tile per k_z block
constexpr int NBLK_Z = (B / TI) * STEP;  // 1024
#define LOG_2PI 1.837877066409345f
#define LOG_C   16.36495572888985f       // log(256 * 50000)

__device__ __forceinline__ float warpReduceSum64(float v) {
    for (int o = 32; o > 0; o >>= 1) v += __shfl_down(v, o, 64);
    return v;
}

// 256-thread block reduction; lds4 = float[4]; result valid in ALL threads.
__device__ __forceinline__ float blockReduceSum256(float v, float* lds4) {
    int wid = threadIdx.x >> 6, lane = threadIdx.x & 63;
    v = warpReduceSum64(v);
    if (lane == 0) lds4[wid] = v;
    __syncthreads();
    float r = lds4[0] + lds4[1] + lds4[2] + lds4[3];
    __syncthreads();
    return r;
}

// 512-thread block reductions; lds8 = float[8].
__device__ __forceinline__ float blockReduceSum512(float v, float* lds8) {
    int wid = threadIdx.x >> 6, lane = threadIdx.x & 63;
    v = warpReduceSum64(v);
    if (lane == 0) lds8[wid] = v;
    __syncthreads();
    float r = 0.0f;
#pragma unroll
    for (int k = 0; k < 8; ++k) r += lds8[k];
    __syncthreads();
    return r;
}
__device__ __forceinline__ float blockReduceMax512(float v, float* lds8) {
    int wid = threadIdx.x >> 6, lane = threadIdx.x & 63;
    for (int o = 32; o > 0; o >>= 1) v = fmaxf(v, __shfl_down(v, o, 64));
    if (lane == 0) lds8[wid] = v;
    __syncthreads();
    float r = -INFINITY;
#pragma unroll
    for (int k = 0; k < 8; ++k) r = fmaxf(r, lds8[k]);
    __syncthreads();
    return r;
}

// k_pre: tiled LDS transpose with transform. Coalesced reads AND writes.
//  blocks 0..127:  z -> ezt[s][d][j] (rows 0..63 = e, 64..127 = m*e), wc.
//  blocks 128..131: f -> eft (rows 0..255 = e, 256..511 = m*e), wcf.
__global__ __launch_bounds__(256) void k_pre(
        const float* __restrict__ fm, const float* __restrict__ fl,
        const float* __restrict__ zm, const float* __restrict__ zl,
        float* __restrict__ ezt, float* __restrict__ wc,
        float* __restrict__ eft, float* __restrict__ wcf,
        int* __restrict__ counter) {
    int t = threadIdx.x;
    int wv = t >> 6, ln = t & 63;
    __shared__ float te[64][65], tme[64][65];   // padded: conflict-free both axes
    if (blockIdx.x == 0 && t == 0) *counter = 0;

    if (blockIdx.x < 128) {
        int s = blockIdx.x >> 2, j0 = (blockIdx.x & 3) * 64;
#pragma unroll 4
        for (int it = 0; it < 16; ++it) {
            int jr = it * 4 + wv, j = j0 + jr;
            size_t src = ((size_t)j * STEP + s) * DZ + ln;   // 256B coalesced per wave
            float lv = zl[src], m = zm[src];
            float e = __expf(-lv);
            te[ln][jr] = e;
            tme[ln][jr] = m * e;
            float r = warpReduceSum64(2.0f * lv);
            if (ln == 0) wc[s * B + j] = r + (float)DZ * LOG_2PI;
        }
        __syncthreads();
#pragma unroll 4
        for (int it = 0; it < 16; ++it) {
            int dr = it * 4 + wv;
            ezt[((size_t)s * 128 + dr) * B + j0 + ln] = te[dr][ln];       // 256B coalesced
            ezt[((size_t)s * 128 + 64 + dr) * B + j0 + ln] = tme[dr][ln];
        }
    } else {
        int j0 = (blockIdx.x - 128) * 64;
        __shared__ float wsh[64];
        if (t < 64) wsh[t] = 0.0f;
        __syncthreads();
        for (int dt = 0; dt < 4; ++dt) {
            int d0 = dt * 64;
#pragma unroll 4
            for (int it = 0; it < 16; ++it) {
                int jr = it * 4 + wv, j = j0 + jr;
                size_t src = (size_t)j * DF + d0 + ln;
                float lv = fl[src], m = fm[src];
                float e = __expf(-lv);
                te[ln][jr] = e;
                tme[ln][jr] = m * e;
                float r = warpReduceSum64(2.0f * lv);
                if (ln == 0) wsh[jr] += r;     // same thread each dt -> deterministic
            }
            __syncthreads();
#pragma unroll 4
            for (int it = 0; it < 16; ++it) {
                int dr = it * 4 + wv;
                eft[(size_t)(d0 + dr) * B + j0 + ln] = te[dr][ln];
                eft[(size_t)(256 + d0 + dr) * B + j0 + ln] = tme[dr][ln];
            }
            __syncthreads();
        }
        if (t < 64) wcf[j0 + t] = wsh[t] + (float)DF * LOG_2PI;
    }
}

// k_f: grid = B (i), block = 512 (t = half*256 + j). All eft loads scalar-coalesced.
__global__ __launch_bounds__(512, 2) void k_f(
        const float* __restrict__ fs, const float* __restrict__ eft,
        const float* __restrict__ wcf,
        float* __restrict__ sum_f, float* __restrict__ hneg_f) {
    int i = blockIdx.x, t = threadIdx.x;
    int j = t & (B - 1), half = t >> 8;
    __shared__ float fs_sh[DF];
    __shared__ float pacc[2][B];
    __shared__ float lds8[8];
    if (t < DF) fs_sh[t] = fs[(size_t)i * DF + t];
    __syncthreads();

    const float* ep = eft + (size_t)(half * 128) * B + j;         // e rows
    const float* mp = eft + (size_t)(256 + half * 128) * B + j;   // me rows
    const float4* fs4 = reinterpret_cast<const float4*>(fs_sh) + half * 32;
    float acc = 0.0f;
#pragma unroll 4
    for (int c = 0; c < 32; ++c) {
        float4 sv = fs4[c];
        float e0 = ep[(size_t)(c * 4 + 0) * B], e1 = ep[(size_t)(c * 4 + 1) * B];
        float e2 = ep[(size_t)(c * 4 + 2) * B], e3 = ep[(size_t)(c * 4 + 3) * B];
        float m0 = mp[(size_t)(c * 4 + 0) * B], m1 = mp[(size_t)(c * 4 + 1) * B];
        float m2 = mp[(size_t)(c * 4 + 2) * B], m3 = mp[(size_t)(c * 4 + 3) * B];
        float t0 = fmaf(sv.x, e0, -m0);
        float t1 = fmaf(sv.y, e1, -m1);
        float t2 = fmaf(sv.z, e2, -m2);
        float t3 = fmaf(sv.w, e3, -m3);
        acc = fmaf(t0, t0, acc); acc = fmaf(t1, t1, acc);
        acc = fmaf(t2, t2, acc); acc = fmaf(t3, t3, acc);
    }
    pacc[half][j] = acc;
    __syncthreads();

    float val = -INFINITY;
    if (t < B) {
        val = -0.5f * (pacc[0][j] + pacc[1][j] + wcf[j]);
        sum_f[(size_t)i * B + j] = val;
    }
    float m = blockReduceMax512(val, lds8);
    float ssum = blockReduceSum512(t < B ? __expf(val - m) : 0.0f, lds8);
    if (t == 0) hneg_f[i] = fmaxf(-(m + __logf(ssum) - LOG_C), 0.0f);
}

// k_z: grid = (B/TI, STEP), block = 256 (j). Coalesced ezt reads; wave-level LSE;
// fused deterministic final reduction (counter self-resets each call).
__global__ __launch_bounds__(256, 2) void k_z(
        const float* __restrict__ ezt, const float* __restrict__ wc,
        const float* __restrict__ zs,
        const float* __restrict__ sum_f, const float* __restrict__ hneg_f,
        float* __restrict__ partials, int* __restrict__ counter,
        float* __restrict__ out) {
    int it = blockIdx.x, s = blockIdx.y, j = threadIdx.x;
    int i0 = it * TI;
    int bid = s * (B / TI) + it;
    int wv = j >> 6, ln = j & 63;
    __shared__ float zs_sh[TI][DZ];            // 2 KB
    __shared__ float wm[4][TI][2], wsum[4][TI][2];
    __shared__ float hbuf[2 * TI];
    __shared__ float lds4[4];
    __shared__ int   is_last;

    {   // stage TI zs rows (each row 256B contiguous)
        if (j < TI * DZ / 4) {
            int ii = j >> 4, c = j & 15;
            float4 v = *reinterpret_cast<const float4*>(
                &zs[((size_t)(i0 + ii) * STEP + s) * DZ + c * 4]);
            *reinterpret_cast<float4*>(&zs_sh[ii][c * 4]) = v;
        }
    }
    __syncthreads();

    const float* ep = ezt + (size_t)s * 128 * B + j;   // e rows, lane-coalesced
    const float* mp = ep + (size_t)64 * B;             // me rows
    float acc[TI];
#pragma unroll
    for (int i = 0; i < TI; ++i) acc[i] = 0.0f;
#pragma unroll 2
    for (int c = 0; c < 16; ++c) {
        float e0 = ep[(size_t)(c * 4 + 0) * B], e1 = ep[(size_t)(c * 4 + 1) * B];
        float e2 = ep[(size_t)(c * 4 + 2) * B], e3 = ep[(size_t)(c * 4 + 3) * B];
        float m0 = mp[(size_t)(c * 4 + 0) * B], m1 = mp[(size_t)(c * 4 + 1) * B];
        float m2 = mp[(size_t)(c * 4 + 2) * B], m3 = mp[(size_t)(c * 4 + 3) * B];
#pragma unroll
        for (int i = 0; i < TI; ++i) {
            float4 sv = *reinterpret_cast<const float4*>(&zs_sh[i][c * 4]);  // broadcast
            float t0 = fmaf(sv.x, e0, -m0);
            float t1 = fmaf(sv.y, e1, -m1);
            float t2 = fmaf(sv.z, e2, -m2);
            float t3 = fmaf(sv.w, e3, -m3);
            acc[i] = fmaf(t0, t0, acc[i]);
            acc[i] = fmaf(t1, t1, acc[i]);
            acc[i] = fmaf(t2, t2, acc[i]);
            acc[i] = fmaf(t3, t3, acc[i]);
        }
    }
    float wcj = wc[s * B + j];

    // Per-wave LSE over this wave's 64 j's, then 4-way combine.
#pragma unroll
    for (int i = 0; i < TI; ++i) {
        float sz = -0.5f * (acc[i] + wcj);
        float szf = sz + sum_f[(size_t)(i0 + i) * B + j];
        float m = sz;
        for (int o = 32; o > 0; o >>= 1) m = fmaxf(m, __shfl_xor(m, o, 64));
        float p = __expf(sz - m);
        for (int o = 32; o > 0; o >>= 1) p += __shfl_xor(p, o, 64);
        if (ln == 0) { wm[wv][i][0] = m; wsum[wv][i][0] = p; }
        float m2 = szf;
        for (int o = 32; o > 0; o >>= 1) m2 = fmaxf(m2, __shfl_xor(m2, o, 64));
        float p2 = __expf(szf - m2);
        for (int o = 32; o > 0; o >>= 1) p2 += __shfl_xor(p2, o, 64);
        if (ln == 0) { wm[wv][i][1] = m2; wsum[wv][i][1] = p2; }
    }
    __syncthreads();

    if (j < 2 * TI) {
        int i = j >> 1, ty = j & 1;
        float m0 = wm[0][i][ty], m1 = wm[1][i][ty], m2 = wm[2][i][ty], m3 = wm[3][i][ty];
        float mm = fmaxf(fmaxf(m0, m1), fmaxf(m2, m3));
        float ss = wsum[0][i][ty] * __expf(m0 - mm) + wsum[1][i][ty] * __expf(m1 - mm)
                 + wsum[2][i][ty] * __expf(m2 - mm) + wsum[3][i][ty] * __expf(m3 - mm);
        float lq = mm + __logf(ss) - LOG_C;
        hbuf[j] = fmaxf(-lq, 0.0f);
    }
    __syncthreads();

    if (j == 0) {
        float pz = 0.0f, pfz = 0.0f;
#pragma unroll
        for (int i = 0; i < TI; ++i) { pz += hbuf[2 * i]; pfz += hbuf[2 * i + 1]; }
        __hip_atomic_store(&partials[2 * bid], pz, __ATOMIC_RELAXED, __HIP_MEMORY_SCOPE_AGENT);
        __hip_atomic_store(&partials[2 * bid + 1], pfz, __ATOMIC_RELAXED, __HIP_MEMORY_SCOPE_AGENT);
        __threadfence();
        int old = __hip_atomic_fetch_add(counter, 1, __ATOMIC_ACQ_REL, __HIP_MEMORY_SCOPE_AGENT);
        is_last = (old == NBLK_Z - 1) ? 1 : 0;
    }
    __syncthreads();

    if (is_last) {
        __threadfence();
        float pz = 0.0f, pfz = 0.0f;
#pragma unroll
        for (int r = 0; r < NBLK_Z / B; ++r) {    // 4 per thread
            int b = r * B + j;
            pz  += __hip_atomic_load(&partials[2 * b], __ATOMIC_RELAXED, __HIP_MEMORY_SCOPE_AGENT);
            pfz += __hip_atomic_load(&partials[2 * b + 1], __ATOMIC_RELAXED, __HIP_MEMORY_SCOPE_AGENT);
        }
        float hf = hneg_f[j];
        float Hz  = blockReduceSum256(pz, lds4) * (1.0f / (STEP * B));
        float Hfz = blockReduceSum256(pfz, lds4) * (1.0f / (STEP * B));
        float Hf  = blockReduceSum256(hf, lds4) * (1.0f / B);
        if (j == 0) {
            out[0] = Hf + Hz - Hfz;
            __hip_atomic_store(counter, 0, __ATOMIC_RELEASE, __HIP_MEMORY_SCOPE_AGENT);
        }
    }
}

extern "C" void kernel_launch(void* const* d_in, const int* in_sizes, int n_in,
                              void* d_out, int out_size, void* d_ws, size_t ws_size,
                              hipStream_t stream) {
    const float* f_mean   = (const float*)d_in[0];
    const float* f_logvar = (const float*)d_in[1];
    const float* f_sample = (const float*)d_in[2];
    const float* z_mean   = (const float*)d_in[3];
    const float* z_logvar = (const float*)d_in[4];
    const float* z_sample = (const float*)d_in[5];
    float* out = (float*)d_out;

    float* w = (float*)d_ws;
    float* sum_f    = w;  w += B * B;               // 65536
    float* hneg_f   = w;  w += B;                   // 256
    float* partials = w;  w += 2 * NBLK_Z;          // 2048
    int*   counter  = (int*)w;  w += 64;            // padded
    float* ezt      = w;  w += STEP * 2 * DZ * B;   // 1048576 (4 MB), [s][128][256]
    float* wc       = w;  w += STEP * B;            // 8192
    float* eft      = w;  w += 2 * DF * B;          // 131072, [512][256]
    float* wcf      = w;  w += B;                   // 256

    k_pre<<<dim3(132), dim3(256), 0, stream>>>(f_mean, f_logvar, z_mean, z_logvar,
                                               ezt, wc, eft, wcf, counter);
    k_f<<<dim3(B), dim3(512), 0, stream>>>(f_sample, eft, wcf, sum_f, hneg_f);
    k_z<<<dim3(B / TI, STEP), dim3(256), 0, stream>>>(ezt, wc, z_sample,
                                                      sum_f, hneg_f, partials,
                                                      counter, out);
}

// Round 7
// 87.394 us; speedup vs baseline: 2.6686x; 1.1316x over previous
//
#include <hip/hip_runtime.h>
#include <math.h>

constexpr int B = 256, STEP = 32, DF = 256, DZ = 64;
constexpr int TI = 8;                    // i-tile per k_z block
constexpr int NBLK_Z = (B / TI) * STEP;  // 1024
#define LOG_2PI 1.837877066409345f
#define LOG_C   16.36495572888985f       // log(256 * 50000)

__device__ __forceinline__ float warpReduceSum64(float v) {
    for (int o = 32; o > 0; o >>= 1) v += __shfl_down(v, o, 64);
    return v;
}

// 256-thread block reduction; lds4 = float[4]; result valid in ALL threads.
__device__ __forceinline__ float blockReduceSum256(float v, float* lds4) {
    int wid = threadIdx.x >> 6, lane = threadIdx.x & 63;
    v = warpReduceSum64(v);
    if (lane == 0) lds4[wid] = v;
    __syncthreads();
    float r = lds4[0] + lds4[1] + lds4[2] + lds4[3];
    __syncthreads();
    return r;
}

// 512-thread block reductions; lds8 = float[8].
__device__ __forceinline__ float blockReduceSum512(float v, float* lds8) {
    int wid = threadIdx.x >> 6, lane = threadIdx.x & 63;
    v = warpReduceSum64(v);
    if (lane == 0) lds8[wid] = v;
    __syncthreads();
    float r = 0.0f;
#pragma unroll
    for (int k = 0; k < 8; ++k) r += lds8[k];
    __syncthreads();
    return r;
}
__device__ __forceinline__ float blockReduceMax512(float v, float* lds8) {
    int wid = threadIdx.x >> 6, lane = threadIdx.x & 63;
    for (int o = 32; o > 0; o >>= 1) v = fmaxf(v, __shfl_down(v, o, 64));
    if (lane == 0) lds8[wid] = v;
    __syncthreads();
    float r = -INFINITY;
#pragma unroll
    for (int k = 0; k < 8; ++k) r = fmaxf(r, lds8[k]);
    __syncthreads();
    return r;
}

// k_pre: tiled LDS transpose with transform. Coalesced reads AND writes.
// Batched (pipelined) shuffle reductions: 16 independent chains per step.
//  blocks 0..127:  z -> ezt[s][d][j] (rows 0..63 = e, 64..127 = m*e), wc.
//  blocks 128..131: f -> eft (rows 0..255 = e, 256..511 = m*e), wcf.
__global__ __launch_bounds__(256) void k_pre(
        const float* __restrict__ fm, const float* __restrict__ fl,
        const float* __restrict__ zm, const float* __restrict__ zl,
        float* __restrict__ ezt, float* __restrict__ wc,
        float* __restrict__ eft, float* __restrict__ wcf,
        int* __restrict__ counter) {
    int t = threadIdx.x;
    int wv = t >> 6, ln = t & 63;
    __shared__ float te[64][65], tme[64][65];   // padded: conflict-free both axes
    if (blockIdx.x == 0 && t == 0) *counter = 0;

    if (blockIdx.x < 128) {
        int s = blockIdx.x >> 2, j0 = (blockIdx.x & 3) * 64;
        float red[16];
#pragma unroll 4
        for (int it = 0; it < 16; ++it) {
            int jr = it * 4 + wv, j = j0 + jr;
            size_t src = ((size_t)j * STEP + s) * DZ + ln;   // 256B coalesced per wave
            float lv = zl[src], m = zm[src];
            float e = __expf(-lv);
            te[ln][jr] = e;
            tme[ln][jr] = m * e;
            red[it] = 2.0f * lv;
        }
#pragma unroll
        for (int o = 32; o > 0; o >>= 1)
#pragma unroll
            for (int k = 0; k < 16; ++k) red[k] += __shfl_xor(red[k], o, 64);
        if (ln == 0) {
#pragma unroll
            for (int k = 0; k < 16; ++k)
                wc[s * B + j0 + k * 4 + wv] = red[k] + (float)DZ * LOG_2PI;
        }
        __syncthreads();
#pragma unroll 4
        for (int it = 0; it < 16; ++it) {
            int dr = it * 4 + wv;
            ezt[((size_t)s * 128 + dr) * B + j0 + ln] = te[dr][ln];       // 256B coalesced
            ezt[((size_t)s * 128 + 64 + dr) * B + j0 + ln] = tme[dr][ln];
        }
    } else {
        int j0 = (blockIdx.x - 128) * 64;
        float red[16];
#pragma unroll
        for (int k = 0; k < 16; ++k) red[k] = 0.0f;
        for (int dt = 0; dt < 4; ++dt) {
            int d0 = dt * 64;
#pragma unroll 4
            for (int it = 0; it < 16; ++it) {
                int jr = it * 4 + wv, j = j0 + jr;
                size_t src = (size_t)j * DF + d0 + ln;
                float lv = fl[src], m = fm[src];
                float e = __expf(-lv);
                te[ln][jr] = e;
                tme[ln][jr] = m * e;
                red[it] += 2.0f * lv;    // same thread each dt -> deterministic
            }
            __syncthreads();
#pragma unroll 4
            for (int it = 0; it < 16; ++it) {
                int dr = it * 4 + wv;
                eft[(size_t)(d0 + dr) * B + j0 + ln] = te[dr][ln];
                eft[(size_t)(256 + d0 + dr) * B + j0 + ln] = tme[dr][ln];
            }
            __syncthreads();
        }
#pragma unroll
        for (int o = 32; o > 0; o >>= 1)
#pragma unroll
            for (int k = 0; k < 16; ++k) red[k] += __shfl_xor(red[k], o, 64);
        if (ln == 0) {
#pragma unroll
            for (int k = 0; k < 16; ++k)
                wcf[j0 + k * 4 + wv] = red[k] + (float)DF * LOG_2PI;
        }
    }
}

// k_f: grid = B (i), block = 512 (t = half*256 + j). All eft loads scalar-coalesced.
__global__ __launch_bounds__(512, 2) void k_f(
        const float* __restrict__ fs, const float* __restrict__ eft,
        const float* __restrict__ wcf,
        float* __restrict__ sum_f, float* __restrict__ hneg_f) {
    int i = blockIdx.x, t = threadIdx.x;
    int j = t & (B - 1), half = t >> 8;
    __shared__ float fs_sh[DF];
    __shared__ float pacc[2][B];
    __shared__ float lds8[8];
    if (t < DF) fs_sh[t] = fs[(size_t)i * DF + t];
    __syncthreads();

    const float* ep = eft + (size_t)(half * 128) * B + j;         // e rows
    const float* mp = eft + (size_t)(256 + half * 128) * B + j;   // me rows
    const float4* fs4 = reinterpret_cast<const float4*>(fs_sh) + half * 32;
    float acc = 0.0f;
#pragma unroll 4
    for (int c = 0; c < 32; ++c) {
        float4 sv = fs4[c];
        float e0 = ep[(size_t)(c * 4 + 0) * B], e1 = ep[(size_t)(c * 4 + 1) * B];
        float e2 = ep[(size_t)(c * 4 + 2) * B], e3 = ep[(size_t)(c * 4 + 3) * B];
        float m0 = mp[(size_t)(c * 4 + 0) * B], m1 = mp[(size_t)(c * 4 + 1) * B];
        float m2 = mp[(size_t)(c * 4 + 2) * B], m3 = mp[(size_t)(c * 4 + 3) * B];
        float t0 = fmaf(sv.x, e0, -m0);
        float t1 = fmaf(sv.y, e1, -m1);
        float t2 = fmaf(sv.z, e2, -m2);
        float t3 = fmaf(sv.w, e3, -m3);
        acc = fmaf(t0, t0, acc); acc = fmaf(t1, t1, acc);
        acc = fmaf(t2, t2, acc); acc = fmaf(t3, t3, acc);
    }
    pacc[half][j] = acc;
    __syncthreads();

    float val = -INFINITY;
    if (t < B) {
        val = -0.5f * (pacc[0][j] + pacc[1][j] + wcf[j]);
        sum_f[(size_t)i * B + j] = val;
    }
    float m = blockReduceMax512(val, lds8);
    float ssum = blockReduceSum512(t < B ? __expf(val - m) : 0.0f, lds8);
    if (t == 0) hneg_f[i] = fmaxf(-(m + __logf(ssum) - LOG_C), 0.0f);
}

// k_z: grid = (B/TI, STEP), block = 256 (j). Coalesced ezt reads; BATCHED wave LSE
// (16 independent shuffle chains -> latency pipelines); fused deterministic finish.
__global__ __launch_bounds__(256) void k_z(
        const float* __restrict__ ezt, const float* __restrict__ wc,
        const float* __restrict__ zs,
        const float* __restrict__ sum_f, const float* __restrict__ hneg_f,
        float* __restrict__ partials, int* __restrict__ counter,
        float* __restrict__ out) {
    int it = blockIdx.x, s = blockIdx.y, j = threadIdx.x;
    int i0 = it * TI;
    int bid = s * (B / TI) + it;
    int wv = j >> 6, ln = j & 63;
    __shared__ float zs_sh[TI][DZ];            // 2 KB
    __shared__ float wm[4][2 * TI], wsum[4][2 * TI];
    __shared__ float hbuf[2 * TI];
    __shared__ float lds4[4];
    __shared__ int   is_last;

    if (j < TI * DZ / 4) {   // stage TI zs rows (each row 256B contiguous)
        int ii = j >> 4, c = j & 15;
        float4 v = *reinterpret_cast<const float4*>(
            &zs[((size_t)(i0 + ii) * STEP + s) * DZ + c * 4]);
        *reinterpret_cast<float4*>(&zs_sh[ii][c * 4]) = v;
    }
    __syncthreads();

    // prefetch j-row constants & sum_f early (hidden under c-loop)
    float wcj = wc[s * B + j];
    float sf[TI];
#pragma unroll
    for (int i = 0; i < TI; ++i) sf[i] = sum_f[(size_t)(i0 + i) * B + j];

    const float* ep = ezt + (size_t)s * 128 * B + j;   // e rows, lane-coalesced
    const float* mp = ep + (size_t)64 * B;             // me rows
    float acc[TI];
#pragma unroll
    for (int i = 0; i < TI; ++i) acc[i] = 0.0f;
#pragma unroll 4
    for (int c = 0; c < 16; ++c) {
        float e0 = ep[(size_t)(c * 4 + 0) * B], e1 = ep[(size_t)(c * 4 + 1) * B];
        float e2 = ep[(size_t)(c * 4 + 2) * B], e3 = ep[(size_t)(c * 4 + 3) * B];
        float m0 = mp[(size_t)(c * 4 + 0) * B], m1 = mp[(size_t)(c * 4 + 1) * B];
        float m2 = mp[(size_t)(c * 4 + 2) * B], m3 = mp[(size_t)(c * 4 + 3) * B];
#pragma unroll
        for (int i = 0; i < TI; ++i) {
            float4 sv = *reinterpret_cast<const float4*>(&zs_sh[i][c * 4]);  // broadcast
            float t0 = fmaf(sv.x, e0, -m0);
            float t1 = fmaf(sv.y, e1, -m1);
            float t2 = fmaf(sv.z, e2, -m2);
            float t3 = fmaf(sv.w, e3, -m3);
            acc[i] = fmaf(t0, t0, acc[i]);
            acc[i] = fmaf(t1, t1, acc[i]);
            acc[i] = fmaf(t2, t2, acc[i]);
            acc[i] = fmaf(t3, t3, acc[i]);
        }
    }

    // ---- batched LSE: 2*TI independent chains, 6 butterfly steps ----
    float v[2 * TI], mx[2 * TI], sm[2 * TI];
#pragma unroll
    for (int i = 0; i < TI; ++i) {
        v[2 * i]     = -0.5f * (acc[i] + wcj);
        v[2 * i + 1] = v[2 * i] + sf[i];
    }
#pragma unroll
    for (int k = 0; k < 2 * TI; ++k) mx[k] = v[k];
#pragma unroll
    for (int o = 32; o > 0; o >>= 1)
#pragma unroll
        for (int k = 0; k < 2 * TI; ++k) mx[k] = fmaxf(mx[k], __shfl_xor(mx[k], o, 64));
#pragma unroll
    for (int k = 0; k < 2 * TI; ++k) sm[k] = __expf(v[k] - mx[k]);
#pragma unroll
    for (int o = 32; o > 0; o >>= 1)
#pragma unroll
        for (int k = 0; k < 2 * TI; ++k) sm[k] += __shfl_xor(sm[k], o, 64);
    if (ln == 0) {
#pragma unroll
        for (int k = 0; k < 2 * TI; ++k) { wm[wv][k] = mx[k]; wsum[wv][k] = sm[k]; }
    }
    __syncthreads();

    if (j < 2 * TI) {   // combine 4 waves per task
        float m0 = wm[0][j], m1 = wm[1][j], m2 = wm[2][j], m3 = wm[3][j];
        float mm = fmaxf(fmaxf(m0, m1), fmaxf(m2, m3));
        float ss = wsum[0][j] * __expf(m0 - mm) + wsum[1][j] * __expf(m1 - mm)
                 + wsum[2][j] * __expf(m2 - mm) + wsum[3][j] * __expf(m3 - mm);
        float lq = mm + __logf(ss) - LOG_C;
        hbuf[j] = fmaxf(-lq, 0.0f);
    }
    __syncthreads();

    if (j == 0) {
        float pz = 0.0f, pfz = 0.0f;
#pragma unroll
        for (int i = 0; i < TI; ++i) { pz += hbuf[2 * i]; pfz += hbuf[2 * i + 1]; }
        __hip_atomic_store(&partials[2 * bid], pz, __ATOMIC_RELAXED, __HIP_MEMORY_SCOPE_AGENT);
        __hip_atomic_store(&partials[2 * bid + 1], pfz, __ATOMIC_RELAXED, __HIP_MEMORY_SCOPE_AGENT);
        __threadfence();
        int old = __hip_atomic_fetch_add(counter, 1, __ATOMIC_ACQ_REL, __HIP_MEMORY_SCOPE_AGENT);
        is_last = (old == NBLK_Z - 1) ? 1 : 0;
    }
    __syncthreads();

    if (is_last) {
        __threadfence();
        float pz = 0.0f, pfz = 0.0f;
#pragma unroll
        for (int r = 0; r < NBLK_Z / B; ++r) {    // 4 per thread
            int b = r * B + j;
            pz  += __hip_atomic_load(&partials[2 * b], __ATOMIC_RELAXED, __HIP_MEMORY_SCOPE_AGENT);
            pfz += __hip_atomic_load(&partials[2 * b + 1], __ATOMIC_RELAXED, __HIP_MEMORY_SCOPE_AGENT);
        }
        float hf = hneg_f[j];
        float Hz  = blockReduceSum256(pz, lds4) * (1.0f / (STEP * B));
        float Hfz = blockReduceSum256(pfz, lds4) * (1.0f / (STEP * B));
        float Hf  = blockReduceSum256(hf, lds4) * (1.0f / B);
        if (j == 0) {
            out[0] = Hf + Hz - Hfz;
            __hip_atomic_store(counter, 0, __ATOMIC_RELEASE, __HIP_MEMORY_SCOPE_AGENT);
        }
    }
}

extern "C" void kernel_launch(void* const* d_in, const int* in_sizes, int n_in,
                              void* d_out, int out_size, void* d_ws, size_t ws_size,
                              hipStream_t stream) {
    const float* f_mean   = (const float*)d_in[0];
    const float* f_logvar = (const float*)d_in[1];
    const float* f_sample = (const float*)d_in[2];
    const float* z_mean   = (const float*)d_in[3];
    const float* z_logvar = (const float*)d_in[4];
    const float* z_sample = (const float*)d_in[5];
    float* out = (float*)d_out;

    float* w = (float*)d_ws;
    float* sum_f    = w;  w += B * B;               // 65536
    float* hneg_f   = w;  w += B;                   // 256
    float* partials = w;  w += 2 * NBLK_Z;          // 2048
    int*   counter  = (int*)w;  w += 64;            // padded
    float* ezt      = w;  w += STEP * 2 * DZ * B;   // 1048576 (4 MB), [s][128][256]
    float* wc       = w;  w += STEP * B;            // 8192
    float* eft      = w;  w += 2 * DF * B;          // 131072, [512][256]
    float* wcf      = w;  w += B;                   // 256

    k_pre<<<dim3(132), dim3(256), 0, stream>>>(f_mean, f_logvar, z_mean, z_logvar,
                                               ezt, wc, eft, wcf, counter);
    k_f<<<dim3(B), dim3(512), 0, stream>>>(f_sample, eft, wcf, sum_f, hneg_f);
    k_z<<<dim3(B / TI, STEP), dim3(256), 0, stream>>>(ezt, wc, z_sample,
                                                      sum_f, hneg_f, partials,
                                                      counter, out);
}

// Round 8
// 84.331 us; speedup vs baseline: 2.7655x; 1.0363x over previous
//
#include <hip/hip_runtime.h>
#include <math.h>

constexpr int B = 256, STEP = 32, DF = 256, DZ = 64;
constexpr int TI = 8;                    // i-tile per k_z block
constexpr int NBLK_Z = (B / TI) * STEP;  // 1024
#define LOG_2PI 1.837877066409345f
#define LOG_C   16.36495572888985f       // log(256 * 50000)

__device__ __forceinline__ float warpReduceSum64(float v) {
    for (int o = 32; o > 0; o >>= 1) v += __shfl_down(v, o, 64);
    return v;
}

// 256-thread block reduction; lds4 = float[4]; result valid in ALL threads.
__device__ __forceinline__ float blockReduceSum256(float v, float* lds4) {
    int wid = threadIdx.x >> 6, lane = threadIdx.x & 63;
    v = warpReduceSum64(v);
    if (lane == 0) lds4[wid] = v;
    __syncthreads();
    float r = lds4[0] + lds4[1] + lds4[2] + lds4[3];
    __syncthreads();
    return r;
}

// 512-thread block reductions; lds8 = float[8].
__device__ __forceinline__ float blockReduceSum512(float v, float* lds8) {
    int wid = threadIdx.x >> 6, lane = threadIdx.x & 63;
    v = warpReduceSum64(v);
    if (lane == 0) lds8[wid] = v;
    __syncthreads();
    float r = 0.0f;
#pragma unroll
    for (int k = 0; k < 8; ++k) r += lds8[k];
    __syncthreads();
    return r;
}
__device__ __forceinline__ float blockReduceMax512(float v, float* lds8) {
    int wid = threadIdx.x >> 6, lane = threadIdx.x & 63;
    for (int o = 32; o > 0; o >>= 1) v = fmaxf(v, __shfl_down(v, o, 64));
    if (lane == 0) lds8[wid] = v;
    __syncthreads();
    float r = -INFINITY;
#pragma unroll
    for (int k = 0; k < 8; ++k) r = fmaxf(r, lds8[k]);
    __syncthreads();
    return r;
}

// k_pre: tiled LDS transpose with transform -> VECTORIZED d-major layouts.
//  blocks 0..127:  z -> ezt4[s][r][j] (float4 rows: r<16 e-chunks, r>=16 me-chunks), wc.
//  blocks 128..131: f -> eft4[r][j]   (r<64 e-chunks, r>=64 me-chunks), wcf.
__global__ __launch_bounds__(256) void k_pre(
        const float* __restrict__ fm, const float* __restrict__ fl,
        const float* __restrict__ zm, const float* __restrict__ zl,
        float4* __restrict__ ezt4, float* __restrict__ wc,
        float4* __restrict__ eft4, float* __restrict__ wcf,
        int* __restrict__ counter) {
    int t = threadIdx.x;
    int wv = t >> 6, ln = t & 63;
    __shared__ float te[64][65], tme[64][65];   // padded: conflict-free both axes
    if (blockIdx.x == 0 && t == 0) *counter = 0;

    if (blockIdx.x < 128) {
        int s = blockIdx.x >> 2, j0 = (blockIdx.x & 3) * 64;
        float red[16];
#pragma unroll 4
        for (int it = 0; it < 16; ++it) {
            int jr = it * 4 + wv, jg = j0 + jr;
            size_t src = ((size_t)jg * STEP + s) * DZ + ln;   // 256B coalesced per wave
            float lv = zl[src], m = zm[src];
            float e = __expf(-lv);
            te[ln][jr] = e;
            tme[ln][jr] = m * e;
            red[it] = 2.0f * lv;
        }
#pragma unroll
        for (int o = 32; o > 0; o >>= 1)
#pragma unroll
            for (int k = 0; k < 16; ++k) red[k] += __shfl_xor(red[k], o, 64);
        if (ln == 0) {
#pragma unroll
            for (int k = 0; k < 16; ++k)
                wc[s * B + j0 + k * 4 + wv] = red[k] + (float)DZ * LOG_2PI;
        }
        __syncthreads();
        float4* ez = ezt4 + (size_t)s * 32 * B;
#pragma unroll
        for (int it = 0; it < 4; ++it) {
            int r = it * 4 + wv;   // chunk 0..15 (dims 4r..4r+3)
            float4 ev = make_float4(te[4 * r + 0][ln], te[4 * r + 1][ln],
                                    te[4 * r + 2][ln], te[4 * r + 3][ln]);
            float4 mv = make_float4(tme[4 * r + 0][ln], tme[4 * r + 1][ln],
                                    tme[4 * r + 2][ln], tme[4 * r + 3][ln]);
            ez[(size_t)r * B + j0 + ln] = ev;          // 1KB coalesced per wave
            ez[(size_t)(16 + r) * B + j0 + ln] = mv;
        }
    } else {
        int j0 = (blockIdx.x - 128) * 64;
        float red[16];
#pragma unroll
        for (int k = 0; k < 16; ++k) red[k] = 0.0f;
        for (int dt = 0; dt < 4; ++dt) {
            int d0 = dt * 64;
#pragma unroll 4
            for (int it = 0; it < 16; ++it) {
                int jr = it * 4 + wv, jg = j0 + jr;
                size_t src = (size_t)jg * DF + d0 + ln;
                float lv = fl[src], m = fm[src];
                float e = __expf(-lv);
                te[ln][jr] = e;
                tme[ln][jr] = m * e;
                red[it] += 2.0f * lv;    // same thread each dt -> deterministic
            }
            __syncthreads();
#pragma unroll
            for (int it2 = 0; it2 < 4; ++it2) {
                int r = it2 * 4 + wv;        // local chunk 0..15
                int gr = dt * 16 + r;        // global chunk 0..63
                float4 ev = make_float4(te[4 * r + 0][ln], te[4 * r + 1][ln],
                                        te[4 * r + 2][ln], te[4 * r + 3][ln]);
                float4 mv = make_float4(tme[4 * r + 0][ln], tme[4 * r + 1][ln],
                                        tme[4 * r + 2][ln], tme[4 * r + 3][ln]);
                eft4[(size_t)gr * B + j0 + ln] = ev;
                eft4[(size_t)(64 + gr) * B + j0 + ln] = mv;
            }
            __syncthreads();
        }
#pragma unroll
        for (int o = 32; o > 0; o >>= 1)
#pragma unroll
            for (int k = 0; k < 16; ++k) red[k] += __shfl_xor(red[k], o, 64);
        if (ln == 0) {
#pragma unroll
            for (int k = 0; k < 16; ++k)
                wcf[j0 + k * 4 + wv] = red[k] + (float)DF * LOG_2PI;
        }
    }
}

// k_f: grid = B (i), block = 512 (t = half*256 + j). float4 coalesced eft reads.
__global__ __launch_bounds__(512, 2) void k_f(
        const float* __restrict__ fs, const float4* __restrict__ eft4,
        const float* __restrict__ wcf,
        float* __restrict__ sum_f, float* __restrict__ hneg_f) {
    int i = blockIdx.x, t = threadIdx.x;
    int j = t & (B - 1), half = t >> 8;
    __shared__ float4 fs_sh[64];
    __shared__ float pacc[2][B];
    __shared__ float lds8[8];
    if (t < 64) fs_sh[t] = reinterpret_cast<const float4*>(fs + (size_t)i * DF)[t];
    __syncthreads();

    const float4* ep = eft4 + (size_t)(half * 32) * B + j;
    const float4* mp = eft4 + (size_t)(64 + half * 32) * B + j;
    float acc = 0.0f;
#pragma unroll 4
    for (int c = 0; c < 32; ++c) {
        float4 e4 = ep[(size_t)c * B];
        float4 me4 = mp[(size_t)c * B];
        float4 sv = fs_sh[half * 32 + c];
        float t0 = fmaf(sv.x, e4.x, -me4.x);
        float t1 = fmaf(sv.y, e4.y, -me4.y);
        float t2 = fmaf(sv.z, e4.z, -me4.z);
        float t3 = fmaf(sv.w, e4.w, -me4.w);
        acc = fmaf(t0, t0, acc); acc = fmaf(t1, t1, acc);
        acc = fmaf(t2, t2, acc); acc = fmaf(t3, t3, acc);
    }
    pacc[half][j] = acc;
    __syncthreads();

    float val = -INFINITY;
    if (t < B) {
        val = -0.5f * (pacc[0][j] + pacc[1][j] + wcf[j]);
        sum_f[(size_t)i * B + j] = val;
    }
    float m = blockReduceMax512(val, lds8);
    float ssum = blockReduceSum512(t < B ? __expf(val - m) : 0.0f, lds8);
    if (t == 0) hneg_f[i] = fmaxf(-(m + __logf(ssum) - LOG_C), 0.0f);
}

// k_z: grid = (B/TI, STEP), block = 256 (j). float4 coalesced panel reads;
// batched wave LSE; fused deterministic finish (counter self-resets).
__global__ __launch_bounds__(256, 4) void k_z(
        const float4* __restrict__ ezt4, const float* __restrict__ wc,
        const float* __restrict__ zs,
        const float* __restrict__ sum_f, const float* __restrict__ hneg_f,
        float* __restrict__ partials, int* __restrict__ counter,
        float* __restrict__ out) {
    int it = blockIdx.x, s = blockIdx.y, j = threadIdx.x;
    int i0 = it * TI;
    int bid = s * (B / TI) + it;
    int wv = j >> 6, ln = j & 63;
    __shared__ float4 zs_sh[TI][16];           // 2 KB
    __shared__ float wm[4][2 * TI], wsum[4][2 * TI];
    __shared__ float hbuf[2 * TI];
    __shared__ float lds4[4];
    __shared__ int   is_last;

    if (j < TI * 16) {   // stage TI zs rows (each row 256B contiguous)
        int ii = j >> 4, c = j & 15;
        zs_sh[ii][c] = *reinterpret_cast<const float4*>(
            &zs[((size_t)(i0 + ii) * STEP + s) * DZ + c * 4]);
    }
    __syncthreads();

    // prefetch j-row constants & sum_f early (hidden under c-loop)
    float wcj = wc[s * B + j];
    float sf[TI];
#pragma unroll
    for (int i = 0; i < TI; ++i) sf[i] = sum_f[(size_t)(i0 + i) * B + j];

    const float4* ev = ezt4 + (size_t)s * 32 * B + j;   // e chunks, lane-coalesced
    const float4* mv = ev + (size_t)16 * B;             // me chunks
    float acc[TI];
#pragma unroll
    for (int i = 0; i < TI; ++i) acc[i] = 0.0f;
#pragma unroll 4
    for (int c = 0; c < 16; ++c) {
        float4 e4 = ev[(size_t)c * B];
        float4 me4 = mv[(size_t)c * B];
#pragma unroll
        for (int i = 0; i < TI; ++i) {
            float4 sv = zs_sh[i][c];               // LDS broadcast (conflict-free)
            float t0 = fmaf(sv.x, e4.x, -me4.x);
            float t1 = fmaf(sv.y, e4.y, -me4.y);
            float t2 = fmaf(sv.z, e4.z, -me4.z);
            float t3 = fmaf(sv.w, e4.w, -me4.w);
            acc[i] = fmaf(t0, t0, acc[i]);
            acc[i] = fmaf(t1, t1, acc[i]);
            acc[i] = fmaf(t2, t2, acc[i]);
            acc[i] = fmaf(t3, t3, acc[i]);
        }
    }

    // ---- batched LSE: 2*TI independent chains, pipelined butterfly steps ----
    float v[2 * TI], mx[2 * TI], sm[2 * TI];
#pragma unroll
    for (int i = 0; i < TI; ++i) {
        v[2 * i]     = -0.5f * (acc[i] + wcj);
        v[2 * i + 1] = v[2 * i] + sf[i];
    }
#pragma unroll
    for (int k = 0; k < 2 * TI; ++k) mx[k] = v[k];
#pragma unroll
    for (int o = 32; o > 0; o >>= 1)
#pragma unroll
        for (int k = 0; k < 2 * TI; ++k) mx[k] = fmaxf(mx[k], __shfl_xor(mx[k], o, 64));
#pragma unroll
    for (int k = 0; k < 2 * TI; ++k) sm[k] = __expf(v[k] - mx[k]);
#pragma unroll
    for (int o = 32; o > 0; o >>= 1)
#pragma unroll
        for (int k = 0; k < 2 * TI; ++k) sm[k] += __shfl_xor(sm[k], o, 64);
    if (ln == 0) {
#pragma unroll
        for (int k = 0; k < 2 * TI; ++k) { wm[wv][k] = mx[k]; wsum[wv][k] = sm[k]; }
    }
    __syncthreads();

    if (j < 2 * TI) {   // combine 4 waves per task
        float m0 = wm[0][j], m1 = wm[1][j], m2 = wm[2][j], m3 = wm[3][j];
        float mm = fmaxf(fmaxf(m0, m1), fmaxf(m2, m3));
        float ss = wsum[0][j] * __expf(m0 - mm) + wsum[1][j] * __expf(m1 - mm)
                 + wsum[2][j] * __expf(m2 - mm) + wsum[3][j] * __expf(m3 - mm);
        float lq = mm + __logf(ss) - LOG_C;
        hbuf[j] = fmaxf(-lq, 0.0f);
    }
    __syncthreads();

    if (j == 0) {
        float pz = 0.0f, pfz = 0.0f;
#pragma unroll
        for (int i = 0; i < TI; ++i) { pz += hbuf[2 * i]; pfz += hbuf[2 * i + 1]; }
        __hip_atomic_store(&partials[2 * bid], pz, __ATOMIC_RELAXED, __HIP_MEMORY_SCOPE_AGENT);
        __hip_atomic_store(&partials[2 * bid + 1], pfz, __ATOMIC_RELAXED, __HIP_MEMORY_SCOPE_AGENT);
        __threadfence();
        int old = __hip_atomic_fetch_add(counter, 1, __ATOMIC_ACQ_REL, __HIP_MEMORY_SCOPE_AGENT);
        is_last = (old == NBLK_Z - 1) ? 1 : 0;
    }
    __syncthreads();

    if (is_last) {
        __threadfence();
        float pz = 0.0f, pfz = 0.0f;
#pragma unroll
        for (int r = 0; r < NBLK_Z / B; ++r) {    // 4 per thread
            int b = r * B + j;
            pz  += __hip_atomic_load(&partials[2 * b], __ATOMIC_RELAXED, __HIP_MEMORY_SCOPE_AGENT);
            pfz += __hip_atomic_load(&partials[2 * b + 1], __ATOMIC_RELAXED, __HIP_MEMORY_SCOPE_AGENT);
        }
        float hf = hneg_f[j];
        float Hz  = blockReduceSum256(pz, lds4) * (1.0f / (STEP * B));
        float Hfz = blockReduceSum256(pfz, lds4) * (1.0f / (STEP * B));
        float Hf  = blockReduceSum256(hf, lds4) * (1.0f / B);
        if (j == 0) {
            out[0] = Hf + Hz - Hfz;
            __hip_atomic_store(counter, 0, __ATOMIC_RELEASE, __HIP_MEMORY_SCOPE_AGENT);
        }
    }
}

extern "C" void kernel_launch(void* const* d_in, const int* in_sizes, int n_in,
                              void* d_out, int out_size, void* d_ws, size_t ws_size,
                              hipStream_t stream) {
    const float* f_mean   = (const float*)d_in[0];
    const float* f_logvar = (const float*)d_in[1];
    const float* f_sample = (const float*)d_in[2];
    const float* z_mean   = (const float*)d_in[3];
    const float* z_logvar = (const float*)d_in[4];
    const float* z_sample = (const float*)d_in[5];
    float* out = (float*)d_out;

    float* w = (float*)d_ws;
    float* sum_f    = w;  w += B * B;               // 65536
    float* hneg_f   = w;  w += B;                   // 256
    float* partials = w;  w += 2 * NBLK_Z;          // 2048
    int*   counter  = (int*)w;  w += 64;            // padded
    float4* ezt4    = (float4*)w;  w += STEP * 32 * B * 4;   // 4 MB, [s][32][256] float4
    float* wc       = w;  w += STEP * B;            // 8192
    float4* eft4    = (float4*)w;  w += 128 * B * 4;         // 512 KB, [128][256] float4
    float* wcf      = w;  w += B;                   // 256

    k_pre<<<dim3(132), dim3(256), 0, stream>>>(f_mean, f_logvar, z_mean, z_logvar,
                                               ezt4, wc, eft4, wcf, counter);
    k_f<<<dim3(B), dim3(512), 0, stream>>>(f_sample, eft4, wcf, sum_f, hneg_f);
    k_z<<<dim3(B / TI, STEP), dim3(256), 0, stream>>>(ezt4, wc, z_sample,
                                                      sum_f, hneg_f, partials,
                                                      counter, out);
}

// Round 9
// 58.216 us; speedup vs baseline: 4.0062x; 1.4486x over previous
//
#include <hip/hip_runtime.h>
#include <math.h>

constexpr int B = 256, STEP = 32, DF = 256, DZ = 64;
constexpr int TI = 8;                    // i-tile per k_z block
#define LOG_2PI 1.837877066409345f
#define LOG_C   16.36495572888985f       // log(256 * 50000)

__device__ __forceinline__ float warpReduceSum64(float v) {
    for (int o = 32; o > 0; o >>= 1) v += __shfl_down(v, o, 64);
    return v;
}

// 256-thread block reduction; lds4 = float[4]; result valid in ALL threads.
__device__ __forceinline__ float blockReduceSum256(float v, float* lds4) {
    int wid = threadIdx.x >> 6, lane = threadIdx.x & 63;
    v = warpReduceSum64(v);
    if (lane == 0) lds4[wid] = v;
    __syncthreads();
    float r = lds4[0] + lds4[1] + lds4[2] + lds4[3];
    __syncthreads();
    return r;
}

// 512-thread block reductions; lds8 = float[8].
__device__ __forceinline__ float blockReduceSum512(float v, float* lds8) {
    int wid = threadIdx.x >> 6, lane = threadIdx.x & 63;
    v = warpReduceSum64(v);
    if (lane == 0) lds8[wid] = v;
    __syncthreads();
    float r = 0.0f;
#pragma unroll
    for (int k = 0; k < 8; ++k) r += lds8[k];
    __syncthreads();
    return r;
}
__device__ __forceinline__ float blockReduceMax512(float v, float* lds8) {
    int wid = threadIdx.x >> 6, lane = threadIdx.x & 63;
    for (int o = 32; o > 0; o >>= 1) v = fmaxf(v, __shfl_down(v, o, 64));
    if (lane == 0) lds8[wid] = v;
    __syncthreads();
    float r = -INFINITY;
#pragma unroll
    for (int k = 0; k < 8; ++k) r = fmaxf(r, lds8[k]);
    __syncthreads();
    return r;
}

// k_pre: tiled LDS transpose with transform -> VECTORIZED d-major layouts.
//  blocks 0..127:  z -> ezt4[s][r][j] (float4 rows: r<16 e-chunks, r>=16 me-chunks), wc.
//  blocks 128..131: f -> eft4[r][j]   (r<64 e-chunks, r>=64 me-chunks), wcf.
__global__ __launch_bounds__(256) void k_pre(
        const float* __restrict__ fm, const float* __restrict__ fl,
        const float* __restrict__ zm, const float* __restrict__ zl,
        float4* __restrict__ ezt4, float* __restrict__ wc,
        float4* __restrict__ eft4, float* __restrict__ wcf) {
    int t = threadIdx.x;
    int wv = t >> 6, ln = t & 63;
    __shared__ float te[64][65], tme[64][65];   // padded: conflict-free both axes

    if (blockIdx.x < 128) {
        int s = blockIdx.x >> 2, j0 = (blockIdx.x & 3) * 64;
        float red[16];
#pragma unroll 4
        for (int it = 0; it < 16; ++it) {
            int jr = it * 4 + wv, jg = j0 + jr;
            size_t src = ((size_t)jg * STEP + s) * DZ + ln;   // 256B coalesced per wave
            float lv = zl[src], m = zm[src];
            float e = __expf(-lv);
            te[ln][jr] = e;
            tme[ln][jr] = m * e;
            red[it] = 2.0f * lv;
        }
#pragma unroll
        for (int o = 32; o > 0; o >>= 1)
#pragma unroll
            for (int k = 0; k < 16; ++k) red[k] += __shfl_xor(red[k], o, 64);
        if (ln == 0) {
#pragma unroll
            for (int k = 0; k < 16; ++k)
                wc[s * B + j0 + k * 4 + wv] = red[k] + (float)DZ * LOG_2PI;
        }
        __syncthreads();
        float4* ez = ezt4 + (size_t)s * 32 * B;
#pragma unroll
        for (int it = 0; it < 4; ++it) {
            int r = it * 4 + wv;   // chunk 0..15 (dims 4r..4r+3)
            float4 ev = make_float4(te[4 * r + 0][ln], te[4 * r + 1][ln],
                                    te[4 * r + 2][ln], te[4 * r + 3][ln]);
            float4 mv = make_float4(tme[4 * r + 0][ln], tme[4 * r + 1][ln],
                                    tme[4 * r + 2][ln], tme[4 * r + 3][ln]);
            ez[(size_t)r * B + j0 + ln] = ev;          // 1KB coalesced per wave
            ez[(size_t)(16 + r) * B + j0 + ln] = mv;
        }
    } else {
        int j0 = (blockIdx.x - 128) * 64;
        float red[16];
#pragma unroll
        for (int k = 0; k < 16; ++k) red[k] = 0.0f;
        for (int dt = 0; dt < 4; ++dt) {
            int d0 = dt * 64;
#pragma unroll 4
            for (int it = 0; it < 16; ++it) {
                int jr = it * 4 + wv, jg = j0 + jr;
                size_t src = (size_t)jg * DF + d0 + ln;
                float lv = fl[src], m = fm[src];
                float e = __expf(-lv);
                te[ln][jr] = e;
                tme[ln][jr] = m * e;
                red[it] += 2.0f * lv;    // same thread each dt -> deterministic
            }
            __syncthreads();
#pragma unroll
            for (int it2 = 0; it2 < 4; ++it2) {
                int r = it2 * 4 + wv;        // local chunk 0..15
                int gr = dt * 16 + r;        // global chunk 0..63
                float4 ev = make_float4(te[4 * r + 0][ln], te[4 * r + 1][ln],
                                        te[4 * r + 2][ln], te[4 * r + 3][ln]);
                float4 mv = make_float4(tme[4 * r + 0][ln], tme[4 * r + 1][ln],
                                        tme[4 * r + 2][ln], tme[4 * r + 3][ln]);
                eft4[(size_t)gr * B + j0 + ln] = ev;
                eft4[(size_t)(64 + gr) * B + j0 + ln] = mv;
            }
            __syncthreads();
        }
#pragma unroll
        for (int o = 32; o > 0; o >>= 1)
#pragma unroll
            for (int k = 0; k < 16; ++k) red[k] += __shfl_xor(red[k], o, 64);
        if (ln == 0) {
#pragma unroll
            for (int k = 0; k < 16; ++k)
                wcf[j0 + k * 4 + wv] = red[k] + (float)DF * LOG_2PI;
        }
    }
}

// k_f: grid = B (i), block = 512 (t = half*256 + j). float4 coalesced eft reads.
__global__ __launch_bounds__(512, 2) void k_f(
        const float* __restrict__ fs, const float4* __restrict__ eft4,
        const float* __restrict__ wcf,
        float* __restrict__ sum_f, float* __restrict__ hneg_f) {
    int i = blockIdx.x, t = threadIdx.x;
    int j = t & (B - 1), half = t >> 8;
    __shared__ float4 fs_sh[64];
    __shared__ float pacc[2][B];
    __shared__ float lds8[8];
    if (t < 64) fs_sh[t] = reinterpret_cast<const float4*>(fs + (size_t)i * DF)[t];
    __syncthreads();

    const float4* ep = eft4 + (size_t)(half * 32) * B + j;
    const float4* mp = eft4 + (size_t)(64 + half * 32) * B + j;
    float acc = 0.0f;
#pragma unroll 4
    for (int c = 0; c < 32; ++c) {
        float4 e4 = ep[(size_t)c * B];
        float4 me4 = mp[(size_t)c * B];
        float4 sv = fs_sh[half * 32 + c];
        float t0 = fmaf(sv.x, e4.x, -me4.x);
        float t1 = fmaf(sv.y, e4.y, -me4.y);
        float t2 = fmaf(sv.z, e4.z, -me4.z);
        float t3 = fmaf(sv.w, e4.w, -me4.w);
        acc = fmaf(t0, t0, acc); acc = fmaf(t1, t1, acc);
        acc = fmaf(t2, t2, acc); acc = fmaf(t3, t3, acc);
    }
    pacc[half][j] = acc;
    __syncthreads();

    float val = -INFINITY;
    if (t < B) {
        val = -0.5f * (pacc[0][j] + pacc[1][j] + wcf[j]);
        sum_f[(size_t)i * B + j] = val;
    }
    float m = blockReduceMax512(val, lds8);
    float ssum = blockReduceSum512(t < B ? __expf(val - m) : 0.0f, lds8);
    if (t == 0) hneg_f[i] = fmaxf(-(m + __logf(ssum) - LOG_C), 0.0f);
}

// k_z: grid = (B/TI, STEP), block = 256 (j). float4 coalesced panel reads;
// batched wave LSE; plain per-element stores (NO fences/atomics in hot path).
__global__ __launch_bounds__(256, 4) void k_z(
        const float4* __restrict__ ezt4, const float* __restrict__ wc,
        const float* __restrict__ zs,
        const float* __restrict__ sum_f,
        float* __restrict__ hneg_z, float* __restrict__ hneg_fz) {
    int it = blockIdx.x, s = blockIdx.y, j = threadIdx.x;
    int i0 = it * TI;
    int wv = j >> 6, ln = j & 63;
    __shared__ float4 zs_sh[TI][16];           // 2 KB
    __shared__ float wm[4][2 * TI], wsum[4][2 * TI];

    if (j < TI * 16) {   // stage TI zs rows (each row 256B contiguous)
        int ii = j >> 4, c = j & 15;
        zs_sh[ii][c] = *reinterpret_cast<const float4*>(
            &zs[((size_t)(i0 + ii) * STEP + s) * DZ + c * 4]);
    }
    __syncthreads();

    // prefetch j-row constants & sum_f early (hidden under c-loop)
    float wcj = wc[s * B + j];
    float sf[TI];
#pragma unroll
    for (int i = 0; i < TI; ++i) sf[i] = sum_f[(size_t)(i0 + i) * B + j];

    const float4* ev = ezt4 + (size_t)s * 32 * B + j;   // e chunks, lane-coalesced
    const float4* mv = ev + (size_t)16 * B;             // me chunks
    float acc[TI];
#pragma unroll
    for (int i = 0; i < TI; ++i) acc[i] = 0.0f;
#pragma unroll 4
    for (int c = 0; c < 16; ++c) {
        float4 e4 = ev[(size_t)c * B];
        float4 me4 = mv[(size_t)c * B];
#pragma unroll
        for (int i = 0; i < TI; ++i) {
            float4 sv = zs_sh[i][c];               // LDS broadcast (conflict-free)
            float t0 = fmaf(sv.x, e4.x, -me4.x);
            float t1 = fmaf(sv.y, e4.y, -me4.y);
            float t2 = fmaf(sv.z, e4.z, -me4.z);
            float t3 = fmaf(sv.w, e4.w, -me4.w);
            acc[i] = fmaf(t0, t0, acc[i]);
            acc[i] = fmaf(t1, t1, acc[i]);
            acc[i] = fmaf(t2, t2, acc[i]);
            acc[i] = fmaf(t3, t3, acc[i]);
        }
    }

    // ---- batched LSE: 2*TI independent chains, pipelined butterfly steps ----
    float v[2 * TI], mx[2 * TI], sm[2 * TI];
#pragma unroll
    for (int i = 0; i < TI; ++i) {
        v[2 * i]     = -0.5f * (acc[i] + wcj);
        v[2 * i + 1] = v[2 * i] + sf[i];
    }
#pragma unroll
    for (int k = 0; k < 2 * TI; ++k) mx[k] = v[k];
#pragma unroll
    for (int o = 32; o > 0; o >>= 1)
#pragma unroll
        for (int k = 0; k < 2 * TI; ++k) mx[k] = fmaxf(mx[k], __shfl_xor(mx[k], o, 64));
#pragma unroll
    for (int k = 0; k < 2 * TI; ++k) sm[k] = __expf(v[k] - mx[k]);
#pragma unroll
    for (int o = 32; o > 0; o >>= 1)
#pragma unroll
        for (int k = 0; k < 2 * TI; ++k) sm[k] += __shfl_xor(sm[k], o, 64);
    if (ln == 0) {
#pragma unroll
        for (int k = 0; k < 2 * TI; ++k) { wm[wv][k] = mx[k]; wsum[wv][k] = sm[k]; }
    }
    __syncthreads();

    if (j < 2 * TI) {   // combine 4 waves per task; write result directly
        float m0 = wm[0][j], m1 = wm[1][j], m2 = wm[2][j], m3 = wm[3][j];
        float mm = fmaxf(fmaxf(m0, m1), fmaxf(m2, m3));
        float ss = wsum[0][j] * __expf(m0 - mm) + wsum[1][j] * __expf(m1 - mm)
                 + wsum[2][j] * __expf(m2 - mm) + wsum[3][j] * __expf(m3 - mm);
        float h = fmaxf(-(mm + __logf(ss) - LOG_C), 0.0f);
        int i = j >> 1;
        if (j & 1) hneg_fz[s * B + i0 + i] = h;
        else       hneg_z[s * B + i0 + i] = h;
    }
}

// k_final: 1 block, deterministic reduction -> scalar.
__global__ __launch_bounds__(256) void k_final(
        const float* __restrict__ hneg_f, const float* __restrict__ hneg_z,
        const float* __restrict__ hneg_fz, float* __restrict__ out) {
    __shared__ float lds4[4];
    int t = threadIdx.x;
    float sf = hneg_f[t];
    float szv = 0.0f, sfz = 0.0f;
#pragma unroll 8
    for (int k = 0; k < STEP; ++k) {       // fixed order per thread -> deterministic
        szv += hneg_z[k * B + t];
        sfz += hneg_fz[k * B + t];
    }
    float Hf  = blockReduceSum256(sf, lds4) * (1.0f / B);
    float Hz  = blockReduceSum256(szv, lds4) * (1.0f / (STEP * B));
    float Hfz = blockReduceSum256(sfz, lds4) * (1.0f / (STEP * B));
    if (t == 0) out[0] = Hf + Hz - Hfz;
}

extern "C" void kernel_launch(void* const* d_in, const int* in_sizes, int n_in,
                              void* d_out, int out_size, void* d_ws, size_t ws_size,
                              hipStream_t stream) {
    const float* f_mean   = (const float*)d_in[0];
    const float* f_logvar = (const float*)d_in[1];
    const float* f_sample = (const float*)d_in[2];
    const float* z_mean   = (const float*)d_in[3];
    const float* z_logvar = (const float*)d_in[4];
    const float* z_sample = (const float*)d_in[5];
    float* out = (float*)d_out;

    float* w = (float*)d_ws;
    float* sum_f    = w;  w += B * B;               // 65536
    float* hneg_f   = w;  w += B;                   // 256
    float* hneg_z   = w;  w += STEP * B;            // 8192
    float* hneg_fz  = w;  w += STEP * B;            // 8192
    float4* ezt4    = (float4*)w;  w += STEP * 32 * B * 4;   // 4 MB, [s][32][256] float4
    float* wc       = w;  w += STEP * B;            // 8192
    float4* eft4    = (float4*)w;  w += 128 * B * 4;         // 512 KB, [128][256] float4
    float* wcf      = w;  w += B;                   // 256

    k_pre<<<dim3(132), dim3(256), 0, stream>>>(f_mean, f_logvar, z_mean, z_logvar,
                                               ezt4, wc, eft4, wcf);
    k_f<<<dim3(B), dim3(512), 0, stream>>>(f_sample, eft4, wcf, sum_f, hneg_f);
    k_z<<<dim3(B / TI, STEP), dim3(256), 0, stream>>>(ezt4, wc, z_sample,
                                                      sum_f, hneg_z, hneg_fz);
    k_final<<<dim3(1), dim3(256), 0, stream>>>(hneg_f, hneg_z, hneg_fz, out);
}

// Round 10
// 57.059 us; speedup vs baseline: 4.0873x; 1.0203x over previous
//
#include <hip/hip_runtime.h>
#include <math.h>

constexpr int B = 256, STEP = 32, DF = 256, DZ = 64;
constexpr int TI = 8;                    // i-tile per k_z block
#define LOG_2PI 1.837877066409345f
#define LOG_C   16.36495572888985f       // log(256 * 50000)

__device__ __forceinline__ float warpReduceSum64(float v) {
    for (int o = 32; o > 0; o >>= 1) v += __shfl_down(v, o, 64);
    return v;
}

// 256-thread block reduction; lds4 = float[4]; result valid in ALL threads.
__device__ __forceinline__ float blockReduceSum256(float v, float* lds4) {
    int wid = threadIdx.x >> 6, lane = threadIdx.x & 63;
    v = warpReduceSum64(v);
    if (lane == 0) lds4[wid] = v;
    __syncthreads();
    float r = lds4[0] + lds4[1] + lds4[2] + lds4[3];
    __syncthreads();
    return r;
}

// k_pre: tiled LDS transpose with transform -> VECTORIZED d-major layouts.
//  blocks 0..127:  z -> ezt4[s][r][j] (float4 rows: r<16 e-chunks, r>=16 me-chunks), wc.
//  blocks 128..131: f -> eft4[r][j]   (r<64 e-chunks, r>=64 me-chunks), wcf.
__global__ __launch_bounds__(256) void k_pre(
        const float* __restrict__ fm, const float* __restrict__ fl,
        const float* __restrict__ zm, const float* __restrict__ zl,
        float4* __restrict__ ezt4, float* __restrict__ wc,
        float4* __restrict__ eft4, float* __restrict__ wcf) {
    int t = threadIdx.x;
    int wv = t >> 6, ln = t & 63;
    __shared__ float te[64][65], tme[64][65];   // padded: conflict-free both axes

    if (blockIdx.x < 128) {
        int s = blockIdx.x >> 2, j0 = (blockIdx.x & 3) * 64;
        float red[16];
#pragma unroll 4
        for (int it = 0; it < 16; ++it) {
            int jr = it * 4 + wv, jg = j0 + jr;
            size_t src = ((size_t)jg * STEP + s) * DZ + ln;   // 256B coalesced per wave
            float lv = zl[src], m = zm[src];
            float e = __expf(-lv);
            te[ln][jr] = e;
            tme[ln][jr] = m * e;
            red[it] = 2.0f * lv;
        }
#pragma unroll
        for (int o = 32; o > 0; o >>= 1)
#pragma unroll
            for (int k = 0; k < 16; ++k) red[k] += __shfl_xor(red[k], o, 64);
        if (ln == 0) {
#pragma unroll
            for (int k = 0; k < 16; ++k)
                wc[s * B + j0 + k * 4 + wv] = red[k] + (float)DZ * LOG_2PI;
        }
        __syncthreads();
        float4* ez = ezt4 + (size_t)s * 32 * B;
#pragma unroll
        for (int it = 0; it < 4; ++it) {
            int r = it * 4 + wv;   // chunk 0..15 (dims 4r..4r+3)
            float4 evv = make_float4(te[4 * r + 0][ln], te[4 * r + 1][ln],
                                     te[4 * r + 2][ln], te[4 * r + 3][ln]);
            float4 mvv = make_float4(tme[4 * r + 0][ln], tme[4 * r + 1][ln],
                                     tme[4 * r + 2][ln], tme[4 * r + 3][ln]);
            ez[(size_t)r * B + j0 + ln] = evv;          // 1KB coalesced per wave
            ez[(size_t)(16 + r) * B + j0 + ln] = mvv;
        }
    } else {
        int j0 = (blockIdx.x - 128) * 64;
        float red[16];
#pragma unroll
        for (int k = 0; k < 16; ++k) red[k] = 0.0f;
        for (int dt = 0; dt < 4; ++dt) {
            int d0 = dt * 64;
#pragma unroll 4
            for (int it = 0; it < 16; ++it) {
                int jr = it * 4 + wv, jg = j0 + jr;
                size_t src = (size_t)jg * DF + d0 + ln;
                float lv = fl[src], m = fm[src];
                float e = __expf(-lv);
                te[ln][jr] = e;
                tme[ln][jr] = m * e;
                red[it] += 2.0f * lv;    // same thread each dt -> deterministic
            }
            __syncthreads();
#pragma unroll
            for (int it2 = 0; it2 < 4; ++it2) {
                int r = it2 * 4 + wv;        // local chunk 0..15
                int gr = dt * 16 + r;        // global chunk 0..63
                float4 evv = make_float4(te[4 * r + 0][ln], te[4 * r + 1][ln],
                                         te[4 * r + 2][ln], te[4 * r + 3][ln]);
                float4 mvv = make_float4(tme[4 * r + 0][ln], tme[4 * r + 1][ln],
                                         tme[4 * r + 2][ln], tme[4 * r + 3][ln]);
                eft4[(size_t)gr * B + j0 + ln] = evv;
                eft4[(size_t)(64 + gr) * B + j0 + ln] = mvv;
            }
            __syncthreads();
        }
#pragma unroll
        for (int o = 32; o > 0; o >>= 1)
#pragma unroll
            for (int k = 0; k < 16; ++k) red[k] += __shfl_xor(red[k], o, 64);
        if (ln == 0) {
#pragma unroll
            for (int k = 0; k < 16; ++k)
                wcf[j0 + k * 4 + wv] = red[k] + (float)DF * LOG_2PI;
        }
    }
}

// k_f: grid = B/2 (2 i's per block), block = 512 (t = half*256 + j).
// Depth-3 software pipeline on the float4 panel loads.
__global__ __launch_bounds__(512, 2) void k_f(
        const float* __restrict__ fs, const float4* __restrict__ eft4,
        const float* __restrict__ wcf,
        float* __restrict__ sum_f, float* __restrict__ hneg_f) {
    int ib = blockIdx.x * 2;
    int t = threadIdx.x;
    int j = t & (B - 1), half = t >> 8;
    __shared__ float4 fs_sh[2][64];
    __shared__ float pacc[2][2][B];    // [half][i][j]
    __shared__ float red2[2][8];
    if (t < 128) {
        int ii = t >> 6, c = t & 63;
        fs_sh[ii][c] = reinterpret_cast<const float4*>(fs + (size_t)(ib + ii) * DF)[c];
    }
    __syncthreads();

    const float4* ep = eft4 + (size_t)(half * 32) * B + j;
    const float4* mp = eft4 + (size_t)(64 + half * 32) * B + j;
    float a0 = 0.0f, a1 = 0.0f;
    float4 eA = ep[0], mA = mp[0];
    float4 eB = ep[(size_t)B], mB = mp[(size_t)B];
    float4 eC = ep[(size_t)2 * B], mC = mp[(size_t)2 * B];
#pragma unroll
    for (int c = 0; c < 32; ++c) {
        float4 eN = make_float4(0.f, 0.f, 0.f, 0.f), mN = eN;
        if (c + 3 < 32) { eN = ep[(size_t)(c + 3) * B]; mN = mp[(size_t)(c + 3) * B]; }
        float4 s0 = fs_sh[0][half * 32 + c];
        float4 s1 = fs_sh[1][half * 32 + c];
        float u0 = fmaf(s0.x, eA.x, -mA.x);
        float u1 = fmaf(s0.y, eA.y, -mA.y);
        float u2 = fmaf(s0.z, eA.z, -mA.z);
        float u3 = fmaf(s0.w, eA.w, -mA.w);
        a0 = fmaf(u0, u0, a0); a0 = fmaf(u1, u1, a0);
        a0 = fmaf(u2, u2, a0); a0 = fmaf(u3, u3, a0);
        float w0 = fmaf(s1.x, eA.x, -mA.x);
        float w1 = fmaf(s1.y, eA.y, -mA.y);
        float w2 = fmaf(s1.z, eA.z, -mA.z);
        float w3 = fmaf(s1.w, eA.w, -mA.w);
        a1 = fmaf(w0, w0, a1); a1 = fmaf(w1, w1, a1);
        a1 = fmaf(w2, w2, a1); a1 = fmaf(w3, w3, a1);
        eA = eB; mA = mB; eB = eC; mB = mC; eC = eN; mC = mN;
    }
    pacc[half][0][j] = a0;
    pacc[half][1][j] = a1;
    __syncthreads();

    float v0 = -INFINITY, v1 = -INFINITY;
    if (t < B) {
        v0 = -0.5f * (pacc[0][0][j] + pacc[1][0][j] + wcf[j]);
        v1 = -0.5f * (pacc[0][1][j] + pacc[1][1][j] + wcf[j]);
        sum_f[(size_t)(ib + 0) * B + j] = v0;
        sum_f[(size_t)(ib + 1) * B + j] = v1;
    }
    // batched 2-chain 512-thread reduce (max then sum)
    int wid = t >> 6, lane = t & 63;
    float m0 = v0, m1 = v1;
#pragma unroll
    for (int o = 32; o > 0; o >>= 1) {
        m0 = fmaxf(m0, __shfl_xor(m0, o, 64));
        m1 = fmaxf(m1, __shfl_xor(m1, o, 64));
    }
    if (lane == 0) { red2[0][wid] = m0; red2[1][wid] = m1; }
    __syncthreads();
    m0 = -INFINITY; m1 = -INFINITY;
#pragma unroll
    for (int k = 0; k < 8; ++k) { m0 = fmaxf(m0, red2[0][k]); m1 = fmaxf(m1, red2[1][k]); }
    __syncthreads();
    float p0 = (t < B) ? __expf(v0 - m0) : 0.0f;
    float p1 = (t < B) ? __expf(v1 - m1) : 0.0f;
#pragma unroll
    for (int o = 32; o > 0; o >>= 1) {
        p0 += __shfl_xor(p0, o, 64);
        p1 += __shfl_xor(p1, o, 64);
    }
    if (lane == 0) { red2[0][wid] = p0; red2[1][wid] = p1; }
    __syncthreads();
    if (t == 0) {
        float s0 = 0.0f, s1 = 0.0f;
#pragma unroll
        for (int k = 0; k < 8; ++k) { s0 += red2[0][k]; s1 += red2[1][k]; }
        hneg_f[ib + 0] = fmaxf(-(m0 + __logf(s0) - LOG_C), 0.0f);
        hneg_f[ib + 1] = fmaxf(-(m1 + __logf(s1) - LOG_C), 0.0f);
    }
}

// k_z: grid = (B/TI, STEP), block = 256 (j). Depth-2 pipelined float4 panel reads;
// batched wave LSE; plain stores (no fences/atomics).
__global__ __launch_bounds__(256, 4) void k_z(
        const float4* __restrict__ ezt4, const float* __restrict__ wc,
        const float* __restrict__ zs,
        const float* __restrict__ sum_f,
        float* __restrict__ hneg_z, float* __restrict__ hneg_fz) {
    int it = blockIdx.x, s = blockIdx.y, j = threadIdx.x;
    int i0 = it * TI;
    int wv = j >> 6, ln = j & 63;
    __shared__ float4 zs_sh[TI][16];           // 2 KB
    __shared__ float wm[4][2 * TI], wsum[4][2 * TI];

    if (j < TI * 16) {   // stage TI zs rows (each row 256B contiguous)
        int ii = j >> 4, c = j & 15;
        zs_sh[ii][c] = *reinterpret_cast<const float4*>(
            &zs[((size_t)(i0 + ii) * STEP + s) * DZ + c * 4]);
    }
    __syncthreads();

    float wcj = wc[s * B + j];
    float sf[TI];
#pragma unroll
    for (int i = 0; i < TI; ++i) sf[i] = sum_f[(size_t)(i0 + i) * B + j];

    const float4* ev = ezt4 + (size_t)s * 32 * B + j;   // e chunks, lane-coalesced
    const float4* mv = ev + (size_t)16 * B;             // me chunks
    float acc[TI];
#pragma unroll
    for (int i = 0; i < TI; ++i) acc[i] = 0.0f;

    // depth-2 software pipeline over the 16 chunks
    float4 eA = ev[0], mA = mv[0];
    float4 eB = ev[(size_t)B], mB = mv[(size_t)B];
#pragma unroll
    for (int c = 0; c < 16; ++c) {
        float4 eN = make_float4(0.f, 0.f, 0.f, 0.f), mN = eN;
        if (c + 2 < 16) { eN = ev[(size_t)(c + 2) * B]; mN = mv[(size_t)(c + 2) * B]; }
#pragma unroll
        for (int i = 0; i < TI; ++i) {
            float4 sv = zs_sh[i][c];               // LDS broadcast (conflict-free)
            float t0 = fmaf(sv.x, eA.x, -mA.x);
            float t1 = fmaf(sv.y, eA.y, -mA.y);
            float t2 = fmaf(sv.z, eA.z, -mA.z);
            float t3 = fmaf(sv.w, eA.w, -mA.w);
            acc[i] = fmaf(t0, t0, acc[i]);
            acc[i] = fmaf(t1, t1, acc[i]);
            acc[i] = fmaf(t2, t2, acc[i]);
            acc[i] = fmaf(t3, t3, acc[i]);
        }
        eA = eB; mA = mB; eB = eN; mB = mN;
    }

    // ---- batched LSE: 2*TI independent chains, pipelined butterfly steps ----
    float v[2 * TI], mx[2 * TI], sm[2 * TI];
#pragma unroll
    for (int i = 0; i < TI; ++i) {
        v[2 * i]     = -0.5f * (acc[i] + wcj);
        v[2 * i + 1] = v[2 * i] + sf[i];
    }
#pragma unroll
    for (int k = 0; k < 2 * TI; ++k) mx[k] = v[k];
#pragma unroll
    for (int o = 32; o > 0; o >>= 1)
#pragma unroll
        for (int k = 0; k < 2 * TI; ++k) mx[k] = fmaxf(mx[k], __shfl_xor(mx[k], o, 64));
#pragma unroll
    for (int k = 0; k < 2 * TI; ++k) sm[k] = __expf(v[k] - mx[k]);
#pragma unroll
    for (int o = 32; o > 0; o >>= 1)
#pragma unroll
        for (int k = 0; k < 2 * TI; ++k) sm[k] += __shfl_xor(sm[k], o, 64);
    if (ln == 0) {
#pragma unroll
        for (int k = 0; k < 2 * TI; ++k) { wm[wv][k] = mx[k]; wsum[wv][k] = sm[k]; }
    }
    __syncthreads();

    if (j < 2 * TI) {   // combine 4 waves per task; write result directly
        float m0 = wm[0][j], m1 = wm[1][j], m2 = wm[2][j], m3 = wm[3][j];
        float mm = fmaxf(fmaxf(m0, m1), fmaxf(m2, m3));
        float ss = wsum[0][j] * __expf(m0 - mm) + wsum[1][j] * __expf(m1 - mm)
                 + wsum[2][j] * __expf(m2 - mm) + wsum[3][j] * __expf(m3 - mm);
        float h = fmaxf(-(mm + __logf(ss) - LOG_C), 0.0f);
        int i = j >> 1;
        if (j & 1) hneg_fz[s * B + i0 + i] = h;
        else       hneg_z[s * B + i0 + i] = h;
    }
}

// k_final: 1 block, deterministic reduction -> scalar.
__global__ __launch_bounds__(256) void k_final(
        const float* __restrict__ hneg_f, const float* __restrict__ hneg_z,
        const float* __restrict__ hneg_fz, float* __restrict__ out) {
    __shared__ float lds4[4];
    int t = threadIdx.x;
    float sf = hneg_f[t];
    float szv = 0.0f, sfz = 0.0f;
#pragma unroll 8
    for (int k = 0; k < STEP; ++k) {       // fixed order per thread -> deterministic
        szv += hneg_z[k * B + t];
        sfz += hneg_fz[k * B + t];
    }
    float Hf  = blockReduceSum256(sf, lds4) * (1.0f / B);
    float Hz  = blockReduceSum256(szv, lds4) * (1.0f / (STEP * B));
    float Hfz = blockReduceSum256(sfz, lds4) * (1.0f / (STEP * B));
    if (t == 0) out[0] = Hf + Hz - Hfz;
}

extern "C" void kernel_launch(void* const* d_in, const int* in_sizes, int n_in,
                              void* d_out, int out_size, void* d_ws, size_t ws_size,
                              hipStream_t stream) {
    const float* f_mean   = (const float*)d_in[0];
    const float* f_logvar = (const float*)d_in[1];
    const float* f_sample = (const float*)d_in[2];
    const float* z_mean   = (const float*)d_in[3];
    const float* z_logvar = (const float*)d_in[4];
    const float* z_sample = (const float*)d_in[5];
    float* out = (float*)d_out;

    float* w = (float*)d_ws;
    float* sum_f    = w;  w += B * B;               // 65536
    float* hneg_f   = w;  w += B;                   // 256
    float* hneg_z   = w;  w += STEP * B;            // 8192
    float* hneg_fz  = w;  w += STEP * B;            // 8192
    float4* ezt4    = (float4*)w;  w += STEP * 32 * B * 4;   // 4 MB, [s][32][256] float4
    float* wc       = w;  w += STEP * B;            // 8192
    float4* eft4    = (float4*)w;  w += 128 * B * 4;         // 512 KB, [128][256] float4
    float* wcf      = w;  w += B;                   // 256

    k_pre<<<dim3(132), dim3(256), 0, stream>>>(f_mean, f_logvar, z_mean, z_logvar,
                                               ezt4, wc, eft4, wcf);
    k_f<<<dim3(B / 2), dim3(512), 0, stream>>>(f_sample, eft4, wcf, sum_f, hneg_f);
    k_z<<<dim3(B / TI, STEP), dim3(256), 0, stream>>>(ezt4, wc, z_sample,
                                                      sum_f, hneg_z, hneg_fz);
    k_final<<<dim3(1), dim3(256), 0, stream>>>(hneg_f, hneg_z, hneg_fz, out);
}